// Round 2
// baseline (863.857 us; speedup 1.0000x reference)
//
#include <hip/hip_runtime.h>
#include <math.h>

// Problem constants (b=1, c=64, t=128, f=128, expand=4, n=16, K=4, r=4)
#define LSEQ 128          // sequence length (both stages)
#define NROW 128          // rows per stage
#define POS (LSEQ*NROW)   // 16384 positions
#define CDIM 64
#define DDIM 256
#define NSTATE 16
#define RDIM 4
#define KCONV 4

// ---------------------------------------------------------------------------
// Stage-1 input prep: seq_in[(fi*128 + t)*64 + cc] = x[(cc*128 + t)*128 + fi]
__global__ __launch_bounds__(256) void k_prep1(const float* __restrict__ x,
                                               float* __restrict__ seq_in) {
    __shared__ float tile[64][65];
    int t   = blockIdx.x & 127;
    int fi0 = (blockIdx.x >> 7) << 6;  // 0 or 64
    int lane = threadIdx.x & 63;
    int r    = threadIdx.x >> 6;       // 0..3
    #pragma unroll
    for (int i = 0; i < 16; i++) {
        int cc = 4*i + r;
        tile[cc][lane] = x[cc*16384 + t*128 + fi0 + lane];
    }
    __syncthreads();
    #pragma unroll
    for (int i = 0; i < 16; i++) {
        int fl = 4*i + r;
        seq_in[(fi0 + fl)*8192 + t*64 + lane] = tile[lane][fl];
    }
}

// Final: out[cc*16384 + t*128 + fi] = s[(t*128+fi)*64 + cc]
__global__ __launch_bounds__(256) void k_final(const float* __restrict__ s,
                                               float* __restrict__ outp) {
    __shared__ float tile[64][65];
    int t   = blockIdx.x & 127;
    int fi0 = (blockIdx.x >> 7) << 6;
    int lane = threadIdx.x & 63;
    int r    = threadIdx.x >> 6;
    #pragma unroll
    for (int i = 0; i < 16; i++) {
        int fl = 4*i + r;
        tile[fl][lane] = s[(((t << 7) + fi0 + fl) << 6) + lane];
    }
    __syncthreads();
    #pragma unroll
    for (int i = 0; i < 16; i++) {
        int cc = 4*i + r;
        outp[cc*16384 + (t << 7) + fi0 + lane] = tile[lane][cc];
    }
}

// rstd per position: rsqrt(mean(x^2) + 1e-5). One wave per position.
__global__ __launch_bounds__(256) void k_rstd(const float* __restrict__ seq_in,
                                              float* __restrict__ rstd) {
    int p    = blockIdx.x*4 + (threadIdx.x >> 6);
    int lane = threadIdx.x & 63;
    float v = seq_in[p*64 + lane];
    float s = v*v;
    #pragma unroll
    for (int off = 32; off; off >>= 1) s += __shfl_xor(s, off, 64);
    if (lane == 0) rstd[p] = rsqrtf(s*(1.0f/64.0f) + 1e-5f);
}

// ---------------------------------------------------------------------------
// in_proj, both directions in one launch.
// grid = 2 * POS/32 blocks of 512 threads; 32 positions per block; thread j
// owns output channel j (j<256 -> xc_pre, else -> z).
__global__ __launch_bounds__(512) void k_inproj(const float* __restrict__ seq_in,
                                                const float* __restrict__ rstd,
                                                const float* __restrict__ nw_s,
                                                const float* __restrict__ ipw_s,
                                                float* __restrict__ xc_pre,
                                                float* __restrict__ zbuf) {
    __shared__ float xn[32][64];
    int dir = blockIdx.x >> 9;               // POS/32 = 512 blocks per dir
    int g0  = (blockIdx.x & 511) << 5;
    size_t dirOff = (size_t)dir * POS * DDIM;
    const float* nw  = nw_s  + dir*CDIM;
    const float* ipw = ipw_s + (size_t)dir * 2*DDIM*CDIM;

    for (int i = threadIdx.x; i < 32*64; i += 512) {
        int pi = i >> 6, k = i & 63;
        int p = g0 + pi;
        int row = p >> 7, tau = p & 127;
        int s = dir ? (127 - tau) : tau;
        int q = (row << 7) + s;
        xn[pi][k] = seq_in[(q << 6) + k] * rstd[q] * nw[k];
    }
    __syncthreads();

    int j = threadIdx.x;
    const float4* w4 = (const float4*)(ipw + (j << 6));
    float acc[32];
    #pragma unroll
    for (int i = 0; i < 32; i++) acc[i] = 0.f;
    #pragma unroll
    for (int k4 = 0; k4 < 16; k4++) {
        float4 wv = w4[k4];
        #pragma unroll
        for (int i = 0; i < 32; i++) {
            float4 xv = *((const float4*)&xn[i][k4 << 2]);
            acc[i] += wv.x*xv.x + wv.y*xv.y + wv.z*xv.z + wv.w*xv.w;
        }
    }
    float* dst = (j < 256) ? (xc_pre + dirOff + j) : (zbuf + dirOff + (j - 256));
    #pragma unroll
    for (int i = 0; i < 32; i++) dst[(size_t)(g0 + i)*DDIM] = acc[i];
}

// ---------------------------------------------------------------------------
// causal dwconv(K=4)+silu fused with x_proj (256->36), dt_proj (4->256)+softplus,
// B/C extraction. Both dirs in one launch.
// grid = 2 * POS/16 blocks of 256 threads.
__global__ __launch_bounds__(256) void k_convxproj(const float* __restrict__ xc_pre,
                                                   const float* __restrict__ cw_s,
                                                   const float* __restrict__ cb_s,
                                                   const float* __restrict__ xpw_s,
                                                   const float* __restrict__ dtw_s,
                                                   const float* __restrict__ dtb_s,
                                                   float* __restrict__ xcb,
                                                   float* __restrict__ dtout,
                                                   float* __restrict__ bc) {
    __shared__ float pre[19][256];   // xc_pre rows g0-3 .. g0+15
    __shared__ float lx[16][256];    // conv+silu output
    __shared__ float dbl[16][36];
    int dir = blockIdx.x >> 10;      // POS/16 = 1024 blocks per dir
    int g0  = (blockIdx.x & 1023) << 4;
    int tau0 = g0 & 127;
    size_t dirOff = (size_t)dir * POS * DDIM;
    const float* cw  = cw_s  + dir*DDIM*KCONV;
    const float* cb  = cb_s  + dir*DDIM;
    const float* xpw = xpw_s + (size_t)dir*36*DDIM;
    const float* dtw = dtw_s + dir*DDIM*RDIM;
    const float* dtb = dtb_s + dir*DDIM;
    int t = threadIdx.x;

    for (int idx = t; idx < 19*256; idx += 256) {
        int j = idx >> 8, ch = idx & 255;
        float v = 0.f;
        if (!(tau0 == 0 && j < 3))
            v = xc_pre[dirOff + (size_t)(g0 - 3 + j)*DDIM + ch];
        pre[j][ch] = v;
    }
    __syncthreads();

    // conv + silu for this thread's channel at 16 positions
    int ch = t;
    float c0 = cw[ch*4], c1 = cw[ch*4+1], c2 = cw[ch*4+2], c3 = cw[ch*4+3];
    float bv = cb[ch];
    #pragma unroll
    for (int i = 0; i < 16; i++) {
        float a = bv + c0*pre[i][ch] + c1*pre[i+1][ch] + c2*pre[i+2][ch] + c3*pre[i+3][ch];
        float sv = a / (1.f + __expf(-a));
        lx[i][ch] = sv;
        xcb[dirOff + (size_t)(g0 + i)*DDIM + ch] = sv;
    }
    __syncthreads();

    // x_proj: 16 pos x 36 outputs = 576
    #pragma unroll
    for (int rep = 0; rep < 3; rep++) {
        int oid = rep*256 + t;
        if (oid < 576) {
            int pos = oid / 36;
            int j = oid - pos*36;
            const float4* w4 = (const float4*)(xpw + (j << 8));
            const float4* x4 = (const float4*)&lx[pos][0];
            float acc = 0.f;
            for (int k4 = 0; k4 < 64; k4++) {
                float4 wv = w4[k4]; float4 xv = x4[k4];
                acc += wv.x*xv.x + wv.y*xv.y + wv.z*xv.z + wv.w*xv.w;
            }
            dbl[pos][j] = acc;
        }
    }
    __syncthreads();

    // dt for channel t at each of the 16 positions
    float dbv = dtb[t];
    float w0 = dtw[t*4], w1 = dtw[t*4+1], w2 = dtw[t*4+2], w3 = dtw[t*4+3];
    #pragma unroll
    for (int i = 0; i < 16; i++) {
        float a = dbv + dbl[i][0]*w0 + dbl[i][1]*w1 + dbl[i][2]*w2 + dbl[i][3]*w3;
        float sp = (a > 0.f) ? (a + log1pf(__expf(-a))) : log1pf(__expf(a));
        dtout[dirOff + (size_t)(g0 + i)*DDIM + t] = sp;
    }
    // B (16) and C (16) per position
    #pragma unroll
    for (int rep = 0; rep < 2; rep++) {
        int idx = rep*256 + t;
        int pos = idx >> 5, jj = idx & 31;
        bc[(size_t)dir*POS*32 + (size_t)(g0 + pos)*32 + jj] = dbl[pos][4 + jj];
    }
}

// ---------------------------------------------------------------------------
// selective scan; both dirs in one launch. Block = (dir,row,64 channels); each
// channel split over 4 lanes (4 n-states each), shfl-reduced. Fuses +D*xc and
// *silu(z). Writes y in UNREVERSED (q-indexed) layout.
__global__ __launch_bounds__(256) void k_scan(const float* __restrict__ xc,
                                              const float* __restrict__ dt,
                                              const float* __restrict__ bc,
                                              const float* __restrict__ Alog_s,
                                              const float* __restrict__ Dp_s,
                                              const float* __restrict__ zbuf,
                                              float* __restrict__ y) {
    __shared__ float sBC[128*32];   // B[16],C[16] per tau: 16 KiB
    int dir  = blockIdx.x >> 9;     // NROW*4 = 512 blocks per dir
    int rest = blockIdx.x & 511;
    int row  = rest >> 2;
    int ch   = ((rest & 3) << 6) + (threadIdx.x >> 2);
    int ng   = threadIdx.x & 3;     // owns n = ng*4 .. ng*4+3
    size_t dirOff = (size_t)dir * POS * DDIM;
    const float* Alog = Alog_s + dir*DDIM*NSTATE;
    const float* Dp   = Dp_s   + dir*DDIM;

    for (int i = threadIdx.x; i < 128*32; i += 256)
        sBC[i] = bc[(size_t)dir*POS*32 + (size_t)row*4096 + i];
    float a[4], h[4];
    #pragma unroll
    for (int i = 0; i < 4; i++) {
        a[i] = -__expf(Alog[ch*16 + ng*4 + i]);
        h[i] = 0.f;
    }
    float dv = Dp[ch];
    __syncthreads();
    const int pb = row*128;
    for (int tau = 0; tau < 128; tau++) {
        size_t off = dirOff + (size_t)(pb + tau)*DDIM + ch;
        float dtv = dt[off];
        float xv  = xc[off];
        float dtx = dtv*xv;
        float acc = 0.f;
        #pragma unroll
        for (int i = 0; i < 4; i++) {
            float dA = __expf(dtv*a[i]);
            h[i] = h[i]*dA + dtx*sBC[tau*32 + ng*4 + i];
            acc += h[i]*sBC[tau*32 + 16 + ng*4 + i];
        }
        acc += __shfl_xor(acc, 1, 4);
        acc += __shfl_xor(acc, 2, 4);
        if (ng == 0) {
            float yv = acc + dv*xv;
            float zv = zbuf[off];
            yv *= zv / (1.f + __expf(-zv));
            int s = dir ? (127 - tau) : tau;
            y[dirOff + (size_t)((row << 7) + s)*DDIM + ch] = yv;
        }
    }
}

// ---------------------------------------------------------------------------
// out_proj (256->64) for both dirs + bidir residual concat + stage linear
// (128->64) + residual. Optionally writes output transposed (stage-1 -> stage-2
// layout). grid = POS/16 blocks of 256 threads.
__global__ __launch_bounds__(256) void k_outlin(const float* __restrict__ y,  // [2][POS][256], q-layout
                                                const float* __restrict__ opw_s,
                                                const float* __restrict__ seq_in,
                                                const float* __restrict__ lw,
                                                const float* __restrict__ lb,
                                                float* __restrict__ seq_out,
                                                int twrite) {
    __shared__ float ly0[16][256];
    __shared__ float ly1[16][256];
    __shared__ float si[16][64];
    __shared__ float cat[16][128];
    int g0 = blockIdx.x << 4;
    for (int i = threadIdx.x; i < 16*256; i += 256) {
        ly0[i >> 8][i & 255] = y[((size_t)g0 << 8) + i];
        ly1[i >> 8][i & 255] = y[(size_t)POS*DDIM + ((size_t)g0 << 8) + i];
    }
    for (int i = threadIdx.x; i < 16*64; i += 256)
        si[i >> 6][i & 63] = seq_in[((size_t)g0 << 6) + i];
    __syncthreads();

    int cc  = threadIdx.x & 63;
    int sub = threadIdx.x >> 6;
    const float4* wf = (const float4*)(opw_s + (cc << 8));
    const float4* wb = (const float4*)(opw_s + CDIM*DDIM + (cc << 8));
    float accf[4] = {0.f,0.f,0.f,0.f};
    float accb[4] = {0.f,0.f,0.f,0.f};
    for (int k4 = 0; k4 < 64; k4++) {
        float4 wvf = wf[k4];
        float4 wvb = wb[k4];
        #pragma unroll
        for (int ii = 0; ii < 4; ii++) {
            int i = (sub << 2) + ii;
            float4 xf = *((const float4*)&ly0[i][k4 << 2]);
            float4 xb = *((const float4*)&ly1[i][k4 << 2]);
            accf[ii] += wvf.x*xf.x + wvf.y*xf.y + wvf.z*xf.z + wvf.w*xf.w;
            accb[ii] += wvb.x*xb.x + wvb.y*xb.y + wvb.z*xb.z + wvb.w*xb.w;
        }
    }
    #pragma unroll
    for (int ii = 0; ii < 4; ii++) {
        int i = (sub << 2) + ii;
        cat[i][cc]      = si[i][cc] + accf[ii];
        cat[i][64 + cc] = si[i][cc] + accb[ii];
    }
    __syncthreads();

    float accl[4];
    float bv = lb[cc];
    #pragma unroll
    for (int ii = 0; ii < 4; ii++) accl[ii] = bv;
    for (int k = 0; k < 128; k++) {
        float w = lw[k*64 + cc];
        #pragma unroll
        for (int ii = 0; ii < 4; ii++) accl[ii] += cat[(sub << 2) + ii][k]*w;
    }
    #pragma unroll
    for (int ii = 0; ii < 4; ii++) {
        int i = (sub << 2) + ii;
        int p = g0 + i;
        float v = accl[ii] + si[i][cc];
        if (twrite) {
            // stage-1 -> stage-2 layout: dst position (t*128 + fi), p = fi*128 + t
            int dstp = ((p & 127) << 7) + (p >> 7);
            seq_out[((size_t)dstp << 6) + cc] = v;
        } else {
            seq_out[((size_t)p << 6) + cc] = v;
        }
    }
}

// ---------------------------------------------------------------------------
extern "C" void kernel_launch(void* const* d_in, const int* in_sizes, int n_in,
                              void* d_out, int out_size, void* d_ws, size_t ws_size,
                              hipStream_t stream) {
    (void)in_sizes; (void)n_in; (void)out_size; (void)ws_size;
    const float* x      = (const float*)d_in[0];
    const float* norm_w = (const float*)d_in[1];
    const float* ipw    = (const float*)d_in[2];
    const float* cw     = (const float*)d_in[3];
    const float* cb     = (const float*)d_in[4];
    const float* xpw    = (const float*)d_in[5];
    const float* dtw    = (const float*)d_in[6];
    const float* dtbp   = (const float*)d_in[7];
    const float* Alog   = (const float*)d_in[8];
    const float* Dp     = (const float*)d_in[9];
    const float* opw    = (const float*)d_in[10];
    const float* tlw    = (const float*)d_in[11];
    const float* tlb    = (const float*)d_in[12];
    const float* flw    = (const float*)d_in[13];
    const float* flb    = (const float*)d_in[14];
    float* outp = (float*)d_out;

    float* ws       = (float*)d_ws;
    float* seq_in   = ws;                            // POS*64
    float* rstd     = seq_in  + (size_t)POS*64;      // POS
    float* xc_pre   = rstd    + POS;                 // 2*POS*256 (reused as y)
    float* zbuf     = xc_pre  + (size_t)2*POS*256;   // 2*POS*256
    float* xcb      = zbuf    + (size_t)2*POS*256;   // 2*POS*256
    float* dtbuf    = xcb     + (size_t)2*POS*256;   // 2*POS*256
    float* bc       = dtbuf   + (size_t)2*POS*256;   // 2*POS*32
    float* seq_out  = bc      + (size_t)2*POS*32;    // POS*64

    auto stage = [&](int st, const float* lw, const float* lb, int twrite,
                     float* sout) {
        int pi = 2*st;
        k_rstd     <<<POS/4, 256, 0, stream>>>(seq_in, rstd);
        k_inproj   <<<2*POS/32, 512, 0, stream>>>(seq_in, rstd,
                        norm_w + pi*CDIM, ipw + (size_t)pi*2*DDIM*CDIM,
                        xc_pre, zbuf);
        k_convxproj<<<2*POS/16, 256, 0, stream>>>(xc_pre,
                        cw + pi*DDIM*KCONV, cb + pi*DDIM,
                        xpw + (size_t)pi*36*DDIM,
                        dtw + pi*DDIM*RDIM, dtbp + pi*DDIM,
                        xcb, dtbuf, bc);
        k_scan     <<<2*NROW*4, 256, 0, stream>>>(xcb, dtbuf, bc,
                        Alog + (size_t)pi*DDIM*NSTATE, Dp + pi*DDIM,
                        zbuf, xc_pre);   // y written into xc_pre (q-layout)
        k_outlin   <<<POS/16, 256, 0, stream>>>(xc_pre,
                        opw + (size_t)pi*CDIM*DDIM, seq_in, lw, lb,
                        sout, twrite);
    };

    // stage 1 (time mamba), output written directly in stage-2 layout
    k_prep1<<<256, 256, 0, stream>>>(x, seq_in);
    stage(0, tlw, tlb, 1, seq_out);

    // stage 2 (freq mamba)
    {
        float* tmp = seq_in; seq_in = seq_out; seq_out = tmp;
    }
    stage(1, flw, flb, 0, seq_out);

    // write back
    k_final<<<256, 256, 0, stream>>>(seq_out, outp);
}

// Round 3
// 620.372 us; speedup vs baseline: 1.3925x; 1.3925x over previous
//
#include <hip/hip_runtime.h>
#include <math.h>

// Problem constants (b=1, c=64, t=128, f=128, expand=4, n=16, K=4, r=4)
#define LSEQ 128          // sequence length (both stages)
#define NROW 128          // rows per stage
#define POS (LSEQ*NROW)   // 16384 positions
#define CDIM 64
#define DDIM 256
#define NSTATE 16
#define RDIM 4
#define KCONV 4

// ---------------------------------------------------------------------------
// Stage-1 input prep: seq_in[(fi*128 + t)*64 + cc] = x[(cc*128 + t)*128 + fi]
__global__ __launch_bounds__(256) void k_prep1(const float* __restrict__ x,
                                               float* __restrict__ seq_in) {
    __shared__ float tile[64][65];
    int t   = blockIdx.x & 127;
    int fi0 = (blockIdx.x >> 7) << 6;  // 0 or 64
    int lane = threadIdx.x & 63;
    int r    = threadIdx.x >> 6;       // 0..3
    #pragma unroll
    for (int i = 0; i < 16; i++) {
        int cc = 4*i + r;
        tile[cc][lane] = x[cc*16384 + t*128 + fi0 + lane];
    }
    __syncthreads();
    #pragma unroll
    for (int i = 0; i < 16; i++) {
        int fl = 4*i + r;
        seq_in[(fi0 + fl)*8192 + t*64 + lane] = tile[lane][fl];
    }
}

// Final: out[cc*16384 + t*128 + fi] = s[(t*128+fi)*64 + cc]
__global__ __launch_bounds__(256) void k_final(const float* __restrict__ s,
                                               float* __restrict__ outp) {
    __shared__ float tile[64][65];
    int t   = blockIdx.x & 127;
    int fi0 = (blockIdx.x >> 7) << 6;
    int lane = threadIdx.x & 63;
    int r    = threadIdx.x >> 6;
    #pragma unroll
    for (int i = 0; i < 16; i++) {
        int fl = 4*i + r;
        tile[fl][lane] = s[(((t << 7) + fi0 + fl) << 6) + lane];
    }
    __syncthreads();
    #pragma unroll
    for (int i = 0; i < 16; i++) {
        int cc = 4*i + r;
        outp[cc*16384 + (t << 7) + fi0 + lane] = tile[lane][cc];
    }
}

// rstd per position: rsqrt(mean(x^2) + 1e-5). One wave per position.
__global__ __launch_bounds__(256) void k_rstd(const float* __restrict__ seq_in,
                                              float* __restrict__ rstd) {
    int p    = blockIdx.x*4 + (threadIdx.x >> 6);
    int lane = threadIdx.x & 63;
    float v = seq_in[p*64 + lane];
    float s = v*v;
    #pragma unroll
    for (int off = 32; off; off >>= 1) s += __shfl_xor(s, off, 64);
    if (lane == 0) rstd[p] = rsqrtf(s*(1.0f/64.0f) + 1e-5f);
}

// ---------------------------------------------------------------------------
// in_proj, both directions in one launch.
// grid = 2 * POS/32 blocks of 512 threads; 32 positions per block; thread j
// owns output channel j (j<256 -> xc_pre, else -> z).
__global__ __launch_bounds__(512) void k_inproj(const float* __restrict__ seq_in,
                                                const float* __restrict__ rstd,
                                                const float* __restrict__ nw_s,
                                                const float* __restrict__ ipw_s,
                                                float* __restrict__ xc_pre,
                                                float* __restrict__ zbuf) {
    __shared__ float xn[32][64];
    int dir = blockIdx.x >> 9;               // POS/32 = 512 blocks per dir
    int g0  = (blockIdx.x & 511) << 5;
    size_t dirOff = (size_t)dir * POS * DDIM;
    const float* nw  = nw_s  + dir*CDIM;
    const float* ipw = ipw_s + (size_t)dir * 2*DDIM*CDIM;

    for (int i = threadIdx.x; i < 32*64; i += 512) {
        int pi = i >> 6, k = i & 63;
        int p = g0 + pi;
        int row = p >> 7, tau = p & 127;
        int s = dir ? (127 - tau) : tau;
        int q = (row << 7) + s;
        xn[pi][k] = seq_in[(q << 6) + k] * rstd[q] * nw[k];
    }
    __syncthreads();

    int j = threadIdx.x;
    const float4* w4 = (const float4*)(ipw + (j << 6));
    float acc[32];
    #pragma unroll
    for (int i = 0; i < 32; i++) acc[i] = 0.f;
    #pragma unroll
    for (int k4 = 0; k4 < 16; k4++) {
        float4 wv = w4[k4];
        #pragma unroll
        for (int i = 0; i < 32; i++) {
            float4 xv = *((const float4*)&xn[i][k4 << 2]);
            acc[i] += wv.x*xv.x + wv.y*xv.y + wv.z*xv.z + wv.w*xv.w;
        }
    }
    float* dst = (j < 256) ? (xc_pre + dirOff + j) : (zbuf + dirOff + (j - 256));
    #pragma unroll
    for (int i = 0; i < 32; i++) dst[(size_t)(g0 + i)*DDIM] = acc[i];
}

// ---------------------------------------------------------------------------
// causal dwconv(K=4)+silu fused with x_proj (256->36), dt_proj (4->256)+softplus,
// B/C extraction. Both dirs in one launch. Weights staged in LDS.
// grid = 2 * POS/16 blocks of 256 threads.
__global__ __launch_bounds__(256) void k_convxproj(const float* __restrict__ xc_pre,
                                                   const float* __restrict__ cw_s,
                                                   const float* __restrict__ cb_s,
                                                   const float* __restrict__ xpw_s,
                                                   const float* __restrict__ dtw_s,
                                                   const float* __restrict__ dtb_s,
                                                   float* __restrict__ xcb,
                                                   float* __restrict__ dtout,
                                                   float* __restrict__ bc) {
    __shared__ float lx[16][260];    // conv+silu output, padded stride
    __shared__ float w[36][260];     // xpw staged, padded stride
    __shared__ float dbl[16][37];
    int dir = blockIdx.x >> 10;      // POS/16 = 1024 blocks per dir
    int g0  = (blockIdx.x & 1023) << 4;
    int tau0 = g0 & 127;
    size_t dirOff = (size_t)dir * POS * DDIM;
    const float* cw  = cw_s  + dir*DDIM*KCONV;
    const float* cb  = cb_s  + dir*DDIM;
    const float* xpw = xpw_s + (size_t)dir*36*DDIM;
    const float* dtw = dtw_s + dir*DDIM*RDIM;
    const float* dtb = dtb_s + dir*DDIM;
    int t = threadIdx.x;

    // stage weights: 36 rows x 64 float4
    {
        const float4* src = (const float4*)xpw;
        for (int idx4 = t; idx4 < 36*64; idx4 += 256) {
            int j = idx4 >> 6, k4 = idx4 & 63;
            ((float4*)&w[j][0])[k4] = src[idx4];
        }
    }

    // conv + silu for this thread's channel (ch = t) at 16 positions
    float r[19];
    #pragma unroll
    for (int j = 0; j < 19; j++) {
        r[j] = (tau0 == 0 && j < 3) ? 0.f
             : xc_pre[dirOff + (size_t)(g0 - 3 + j)*DDIM + t];
    }
    float c0 = cw[t*4], c1 = cw[t*4+1], c2 = cw[t*4+2], c3 = cw[t*4+3];
    float cbv = cb[t];
    #pragma unroll
    for (int i = 0; i < 16; i++) {
        float a = cbv + c0*r[i] + c1*r[i+1] + c2*r[i+2] + c3*r[i+3];
        float sv = a / (1.f + __expf(-a));
        lx[i][t] = sv;
        xcb[dirOff + (size_t)(g0 + i)*DDIM + t] = sv;
    }
    __syncthreads();

    // x_proj: 16 pos x 36 outputs = 576; oid -> pos = oid&15, j = oid>>4
    #pragma unroll
    for (int rep = 0; rep < 3; rep++) {
        int oid = rep*256 + t;
        if (oid < 576) {
            int pos = oid & 15;
            int j   = oid >> 4;
            const float4* xr = (const float4*)&lx[pos][0];
            const float4* wr = (const float4*)&w[j][0];
            float a0 = 0.f, a1 = 0.f, a2 = 0.f, a3 = 0.f;
            #pragma unroll 4
            for (int k4 = 0; k4 < 64; k4 += 4) {
                float4 x0 = xr[k4],   w0 = wr[k4];
                float4 x1 = xr[k4+1], w1 = wr[k4+1];
                float4 x2 = xr[k4+2], w2 = wr[k4+2];
                float4 x3 = xr[k4+3], w3 = wr[k4+3];
                a0 += x0.x*w0.x + x0.y*w0.y + x0.z*w0.z + x0.w*w0.w;
                a1 += x1.x*w1.x + x1.y*w1.y + x1.z*w1.z + x1.w*w1.w;
                a2 += x2.x*w2.x + x2.y*w2.y + x2.z*w2.z + x2.w*w2.w;
                a3 += x3.x*w3.x + x3.y*w3.y + x3.z*w3.z + x3.w*w3.w;
            }
            dbl[pos][j] = (a0 + a1) + (a2 + a3);
        }
    }
    __syncthreads();

    // dt for channel t at each of the 16 positions
    float dbv = dtb[t];
    float w0 = dtw[t*4], w1 = dtw[t*4+1], w2 = dtw[t*4+2], w3 = dtw[t*4+3];
    #pragma unroll
    for (int i = 0; i < 16; i++) {
        float a = dbv + dbl[i][0]*w0 + dbl[i][1]*w1 + dbl[i][2]*w2 + dbl[i][3]*w3;
        float sp = (a > 0.f) ? (a + log1pf(__expf(-a))) : log1pf(__expf(a));
        dtout[dirOff + (size_t)(g0 + i)*DDIM + t] = sp;
    }
    // B (16) and C (16) per position
    #pragma unroll
    for (int rep = 0; rep < 2; rep++) {
        int idx = rep*256 + t;
        int pos = idx >> 5, jj = idx & 31;
        bc[(size_t)dir*POS*32 + (size_t)(g0 + pos)*32 + jj] = dbl[pos][4 + jj];
    }
}

// ---------------------------------------------------------------------------
// selective scan; both dirs in one launch. Block = (dir,row); thread = channel,
// all 16 n-states in registers. Fuses +D*xc and *silu(z). Writes y in
// UNREVERSED (q-indexed) layout.
__global__ __launch_bounds__(256) void k_scan(const float* __restrict__ xc,
                                              const float* __restrict__ dt,
                                              const float* __restrict__ bc,
                                              const float* __restrict__ Alog_s,
                                              const float* __restrict__ Dp_s,
                                              const float* __restrict__ zbuf,
                                              float* __restrict__ y) {
    __shared__ float sBC[128*32];   // B[16],C[16] per tau: 16 KiB
    int dir = blockIdx.x >> 7;      // 128 blocks per dir
    int row = blockIdx.x & 127;
    int ch  = threadIdx.x;
    size_t dirOff = (size_t)dir * POS * DDIM;
    const float* Alog = Alog_s + dir*DDIM*NSTATE;
    const float* Dp   = Dp_s   + dir*DDIM;

    for (int i = threadIdx.x; i < 128*32; i += 256)
        sBC[i] = bc[(size_t)dir*POS*32 + (size_t)row*4096 + i];
    float a[16], h[16];
    #pragma unroll
    for (int i = 0; i < 16; i++) {
        a[i] = -__expf(Alog[ch*16 + i]);
        h[i] = 0.f;
    }
    float dv = Dp[ch];
    __syncthreads();

    size_t off = dirOff + ((size_t)row*128)*DDIM + ch;
    float dtv = dt[off], xv = xc[off], zv = zbuf[off];
    const size_t ybase = dirOff + ((size_t)row << 7)*DDIM + ch;
    for (int tau = 0; tau < 128; tau++) {
        float dtn = 0.f, xn_ = 0.f, zn = 0.f;
        if (tau < 127) {            // prefetch next position (uniform branch)
            size_t offn = off + DDIM;
            dtn = dt[offn]; xn_ = xc[offn]; zn = zbuf[offn];
        }
        float dtx = dtv*xv;
        const float* B = &sBC[tau*32];
        float ac0 = 0.f, ac1 = 0.f, ac2 = 0.f, ac3 = 0.f;
        #pragma unroll
        for (int i = 0; i < 16; i += 4) {
            float dA0 = __expf(dtv*a[i]);
            float dA1 = __expf(dtv*a[i+1]);
            float dA2 = __expf(dtv*a[i+2]);
            float dA3 = __expf(dtv*a[i+3]);
            h[i]   = h[i]*dA0   + dtx*B[i];
            h[i+1] = h[i+1]*dA1 + dtx*B[i+1];
            h[i+2] = h[i+2]*dA2 + dtx*B[i+2];
            h[i+3] = h[i+3]*dA3 + dtx*B[i+3];
            ac0 += h[i]*B[16+i];
            ac1 += h[i+1]*B[16+i+1];
            ac2 += h[i+2]*B[16+i+2];
            ac3 += h[i+3]*B[16+i+3];
        }
        float yv = (ac0 + ac1) + (ac2 + ac3) + dv*xv;
        yv *= zv / (1.f + __expf(-zv));
        int s = dir ? (127 - tau) : tau;
        y[ybase + (size_t)s*DDIM] = yv;
        dtv = dtn; xv = xn_; zv = zn; off += DDIM;
    }
}

// ---------------------------------------------------------------------------
// out_proj (256->64) for both dirs + bidir residual concat + stage linear
// (128->64) + residual. Optionally writes output transposed (stage-1 -> stage-2
// layout). grid = POS/16 blocks of 256 threads.
__global__ __launch_bounds__(256) void k_outlin(const float* __restrict__ y,  // [2][POS][256], q-layout
                                                const float* __restrict__ opw_s,
                                                const float* __restrict__ seq_in,
                                                const float* __restrict__ lw,
                                                const float* __restrict__ lb,
                                                float* __restrict__ seq_out,
                                                int twrite) {
    __shared__ float ly0[16][256];
    __shared__ float ly1[16][256];
    __shared__ float si[16][64];
    __shared__ float cat[16][128];
    int g0 = blockIdx.x << 4;
    for (int i = threadIdx.x; i < 16*256; i += 256) {
        ly0[i >> 8][i & 255] = y[((size_t)g0 << 8) + i];
        ly1[i >> 8][i & 255] = y[(size_t)POS*DDIM + ((size_t)g0 << 8) + i];
    }
    for (int i = threadIdx.x; i < 16*64; i += 256)
        si[i >> 6][i & 63] = seq_in[((size_t)g0 << 6) + i];
    __syncthreads();

    int cc  = threadIdx.x & 63;
    int sub = threadIdx.x >> 6;
    const float4* wf = (const float4*)(opw_s + (cc << 8));
    const float4* wb = (const float4*)(opw_s + CDIM*DDIM + (cc << 8));
    float accf[4] = {0.f,0.f,0.f,0.f};
    float accb[4] = {0.f,0.f,0.f,0.f};
    for (int k4 = 0; k4 < 64; k4++) {
        float4 wvf = wf[k4];
        float4 wvb = wb[k4];
        #pragma unroll
        for (int ii = 0; ii < 4; ii++) {
            int i = (sub << 2) + ii;
            float4 xf = *((const float4*)&ly0[i][k4 << 2]);
            float4 xb = *((const float4*)&ly1[i][k4 << 2]);
            accf[ii] += wvf.x*xf.x + wvf.y*xf.y + wvf.z*xf.z + wvf.w*xf.w;
            accb[ii] += wvb.x*xb.x + wvb.y*xb.y + wvb.z*xb.z + wvb.w*xb.w;
        }
    }
    #pragma unroll
    for (int ii = 0; ii < 4; ii++) {
        int i = (sub << 2) + ii;
        cat[i][cc]      = si[i][cc] + accf[ii];
        cat[i][64 + cc] = si[i][cc] + accb[ii];
    }
    __syncthreads();

    float accl[4];
    float bv = lb[cc];
    #pragma unroll
    for (int ii = 0; ii < 4; ii++) accl[ii] = bv;
    for (int k = 0; k < 128; k++) {
        float w = lw[k*64 + cc];
        #pragma unroll
        for (int ii = 0; ii < 4; ii++) accl[ii] += cat[(sub << 2) + ii][k]*w;
    }
    #pragma unroll
    for (int ii = 0; ii < 4; ii++) {
        int i = (sub << 2) + ii;
        int p = g0 + i;
        float v = accl[ii] + si[i][cc];
        if (twrite) {
            // stage-1 -> stage-2 layout: dst position (t*128 + fi), p = fi*128 + t
            int dstp = ((p & 127) << 7) + (p >> 7);
            seq_out[((size_t)dstp << 6) + cc] = v;
        } else {
            seq_out[((size_t)p << 6) + cc] = v;
        }
    }
}

// ---------------------------------------------------------------------------
extern "C" void kernel_launch(void* const* d_in, const int* in_sizes, int n_in,
                              void* d_out, int out_size, void* d_ws, size_t ws_size,
                              hipStream_t stream) {
    (void)in_sizes; (void)n_in; (void)out_size; (void)ws_size;
    const float* x      = (const float*)d_in[0];
    const float* norm_w = (const float*)d_in[1];
    const float* ipw    = (const float*)d_in[2];
    const float* cw     = (const float*)d_in[3];
    const float* cb     = (const float*)d_in[4];
    const float* xpw    = (const float*)d_in[5];
    const float* dtw    = (const float*)d_in[6];
    const float* dtbp   = (const float*)d_in[7];
    const float* Alog   = (const float*)d_in[8];
    const float* Dp     = (const float*)d_in[9];
    const float* opw    = (const float*)d_in[10];
    const float* tlw    = (const float*)d_in[11];
    const float* tlb    = (const float*)d_in[12];
    const float* flw    = (const float*)d_in[13];
    const float* flb    = (const float*)d_in[14];
    float* outp = (float*)d_out;

    float* ws       = (float*)d_ws;
    float* seq_in   = ws;                            // POS*64
    float* rstd     = seq_in  + (size_t)POS*64;      // POS
    float* xc_pre   = rstd    + POS;                 // 2*POS*256 (reused as y)
    float* zbuf     = xc_pre  + (size_t)2*POS*256;   // 2*POS*256
    float* xcb      = zbuf    + (size_t)2*POS*256;   // 2*POS*256
    float* dtbuf    = xcb     + (size_t)2*POS*256;   // 2*POS*256
    float* bc       = dtbuf   + (size_t)2*POS*256;   // 2*POS*32
    float* seq_out  = bc      + (size_t)2*POS*32;    // POS*64

    auto stage = [&](int st, const float* lw, const float* lb, int twrite,
                     float* sout) {
        int pi = 2*st;
        k_rstd     <<<POS/4, 256, 0, stream>>>(seq_in, rstd);
        k_inproj   <<<2*POS/32, 512, 0, stream>>>(seq_in, rstd,
                        norm_w + pi*CDIM, ipw + (size_t)pi*2*DDIM*CDIM,
                        xc_pre, zbuf);
        k_convxproj<<<2*POS/16, 256, 0, stream>>>(xc_pre,
                        cw + pi*DDIM*KCONV, cb + pi*DDIM,
                        xpw + (size_t)pi*36*DDIM,
                        dtw + pi*DDIM*RDIM, dtbp + pi*DDIM,
                        xcb, dtbuf, bc);
        k_scan     <<<2*NROW, 256, 0, stream>>>(xcb, dtbuf, bc,
                        Alog + (size_t)pi*DDIM*NSTATE, Dp + pi*DDIM,
                        zbuf, xc_pre);   // y written into xc_pre (q-layout)
        k_outlin   <<<POS/16, 256, 0, stream>>>(xc_pre,
                        opw + (size_t)pi*CDIM*DDIM, seq_in, lw, lb,
                        sout, twrite);
    };

    // stage 1 (time mamba), output written directly in stage-2 layout
    k_prep1<<<256, 256, 0, stream>>>(x, seq_in);
    stage(0, tlw, tlb, 1, seq_out);

    // stage 2 (freq mamba)
    {
        float* tmp = seq_in; seq_in = seq_out; seq_out = tmp;
    }
    stage(1, flw, flb, 0, seq_out);

    // write back
    k_final<<<256, 256, 0, stream>>>(seq_out, outp);
}